// Round 2
// baseline (971.770 us; speedup 1.0000x reference)
//
#include <hip/hip_runtime.h>

#define N_NODES 100000
#define N_EDGES 20000
#define N_INC   1600000
#define NFEAT   256
#define NCLASS  64

// ---------------- histogram: node & edge degrees (int atomics) -----------
__global__ __launch_bounds__(256) void k_count(const int* __restrict__ nidx,
                                               const int* __restrict__ eidx,
                                               int* __restrict__ ncnt,
                                               int* __restrict__ ecnt) {
    int i = blockIdx.x * 256 + threadIdx.x;
    if (i < N_INC) {
        atomicAdd(&ncnt[nidx[i]], 1);
        atomicAdd(&ecnt[eidx[i]], 1);
    }
}

// ---------------- single-block exclusive scan (n <= 1024*chunk) ----------
// writes off[i] = exclusive prefix, cur[i] = same (fill cursor copy)
__global__ __launch_bounds__(1024) void k_scan(const int* __restrict__ cnt,
                                               int* __restrict__ off,
                                               int* __restrict__ cur,
                                               int n) {
    __shared__ int part[1024];
    const int t = threadIdx.x;
    const int chunk = (n + 1023) / 1024;
    const int lo = t * chunk;
    const int hi = min(lo + chunk, n);
    int s = 0;
    for (int i = lo; i < hi; ++i) s += cnt[i];
    part[t] = s;
    __syncthreads();
    // Hillis-Steele inclusive scan over 1024 partials
    for (int d = 1; d < 1024; d <<= 1) {
        int v = (t >= d) ? part[t - d] : 0;
        __syncthreads();
        part[t] += v;
        __syncthreads();
    }
    int run = (t == 0) ? 0 : part[t - 1];
    for (int i = lo; i < hi; ++i) {
        off[i] = run;
        cur[i] = run;
        run += cnt[i];
    }
}

// ---------------- counting-sort fill of CSR incidence lists --------------
__global__ __launch_bounds__(256) void k_fill(const int* __restrict__ nidx,
                                              const int* __restrict__ eidx,
                                              int* __restrict__ ecur,
                                              int* __restrict__ ncur,
                                              int* __restrict__ einc,   // node ids grouped by edge
                                              int* __restrict__ ninc) { // edge ids grouped by node
    int i = blockIdx.x * 256 + threadIdx.x;
    if (i < N_INC) {
        const int n = nidx[i];
        const int e = eidx[i];
        const int pe = atomicAdd(&ecur[e], 1);
        einc[pe] = n;
        const int pn = atomicAdd(&ncur[n], 1);
        ninc[pn] = e;
    }
}

// ---------------- xw = x @ W  (fp32 vector GEMM, 64x64 tile) --------------
__global__ __launch_bounds__(256) void k_gemm(const float* __restrict__ x,
                                              const float* __restrict__ W,
                                              float* __restrict__ xw) {
    __shared__ float xs[64][68];
    __shared__ float wt[64][64];
    const int t  = threadIdx.x;
    const int tr = t >> 4;        // 0..15 (row group of 4)
    const int tc = t & 15;        // 0..15 (col group of 4)
    const int block_row = blockIdx.x * 64;

    float acc[4][4] = {};

    for (int k0 = 0; k0 < NFEAT; k0 += 64) {
        // stage x chunk (64 rows x 64 k), transposed into xs[k][row]
        {
            const int rr = t >> 2;        // 0..63 row within tile
            const int q  = t & 3;         // quarter of the 64 k values
            const int grow = block_row + rr;
            #pragma unroll
            for (int it = 0; it < 4; ++it) {
                const int kk = q * 4 + it * 16;
                float4 v = make_float4(0.f, 0.f, 0.f, 0.f);
                if (grow < N_NODES)
                    v = *(const float4*)&x[(size_t)grow * NFEAT + k0 + kk];
                xs[kk + 0][rr] = v.x;
                xs[kk + 1][rr] = v.y;
                xs[kk + 2][rr] = v.z;
                xs[kk + 3][rr] = v.w;
            }
        }
        // stage W chunk (64 k x 64 c)
        {
            #pragma unroll
            for (int it = 0; it < 4; ++it) {
                const int k = tr + it * 16;
                *(float4*)&wt[k][tc * 4] =
                    *(const float4*)&W[(size_t)(k0 + k) * NCLASS + tc * 4];
            }
        }
        __syncthreads();

        #pragma unroll 16
        for (int kk = 0; kk < 64; ++kk) {
            const float4 xv = *(const float4*)&xs[kk][tr * 4];
            const float4 wv = *(const float4*)&wt[kk][tc * 4];
            const float xa[4] = {xv.x, xv.y, xv.z, xv.w};
            const float wa[4] = {wv.x, wv.y, wv.z, wv.w};
            #pragma unroll
            for (int i2 = 0; i2 < 4; ++i2)
                #pragma unroll
                for (int j2 = 0; j2 < 4; ++j2)
                    acc[i2][j2] = fmaf(xa[i2], wa[j2], acc[i2][j2]);
        }
        __syncthreads();
    }

    #pragma unroll
    for (int i2 = 0; i2 < 4; ++i2) {
        const int r = block_row + tr * 4 + i2;
        if (r < N_NODES) {
            float4 v = make_float4(acc[i2][0], acc[i2][1], acc[i2][2], acc[i2][3]);
            *(float4*)&xw[(size_t)r * NCLASS + tc * 4] = v;
        }
    }
}

// ---------------- per-edge pull gather: e_feat = (sum xw[members]) / deg --
// one wave per edge; lane = channel (NCLASS == 64 == wave size)
__global__ __launch_bounds__(256) void k_edge_gather(const int* __restrict__ einc,
                                                     const int* __restrict__ eoff,
                                                     const int* __restrict__ ecnt,
                                                     const float* __restrict__ xw,
                                                     float* __restrict__ e_feat) {
    const int wave = (blockIdx.x * 256 + threadIdx.x) >> 6;
    const int lane = threadIdx.x & 63;
    if (wave >= N_EDGES) return;
    const int base = eoff[wave];
    const int deg  = ecnt[wave];
    float a0 = 0.f, a1 = 0.f, a2 = 0.f, a3 = 0.f;
    int j = base;
    const int end = base + deg;
    for (; j + 4 <= end; j += 4) {
        const int n0 = einc[j], n1 = einc[j + 1], n2 = einc[j + 2], n3 = einc[j + 3];
        a0 += xw[(size_t)n0 * NCLASS + lane];
        a1 += xw[(size_t)n1 * NCLASS + lane];
        a2 += xw[(size_t)n2 * NCLASS + lane];
        a3 += xw[(size_t)n3 * NCLASS + lane];
    }
    for (; j < end; ++j) a0 += xw[(size_t)einc[j] * NCLASS + lane];
    const float s = (a0 + a1) + (a2 + a3);
    e_feat[(size_t)wave * NCLASS + lane] = (deg > 0) ? s / (float)deg : 0.f;
}

// ---------------- per-node pull gather + Dinv + bias + relu ---------------
__global__ __launch_bounds__(256) void k_node_gather(const int* __restrict__ ninc,
                                                     const int* __restrict__ noff,
                                                     const int* __restrict__ ncnt,
                                                     const float* __restrict__ e_feat,
                                                     const float* __restrict__ b,
                                                     float* __restrict__ out) {
    const int wave = (blockIdx.x * 256 + threadIdx.x) >> 6;
    const int lane = threadIdx.x & 63;
    if (wave >= N_NODES) return;
    const int base = noff[wave];
    const int deg  = ncnt[wave];
    float a0 = 0.f, a1 = 0.f, a2 = 0.f, a3 = 0.f;
    int j = base;
    const int end = base + deg;
    for (; j + 4 <= end; j += 4) {
        const int e0 = ninc[j], e1 = ninc[j + 1], e2 = ninc[j + 2], e3 = ninc[j + 3];
        a0 += e_feat[(size_t)e0 * NCLASS + lane];
        a1 += e_feat[(size_t)e1 * NCLASS + lane];
        a2 += e_feat[(size_t)e2 * NCLASS + lane];
        a3 += e_feat[(size_t)e3 * NCLASS + lane];
    }
    for (; j < end; ++j) a0 += e_feat[(size_t)ninc[j] * NCLASS + lane];
    const float s = (a0 + a1) + (a2 + a3);
    const float r = (deg > 0) ? s / (float)deg : 0.f;
    out[(size_t)wave * NCLASS + lane] = fmaxf(r + b[lane], 0.f);
}

extern "C" void kernel_launch(void* const* d_in, const int* in_sizes, int n_in,
                              void* d_out, int out_size, void* d_ws, size_t ws_size,
                              hipStream_t stream) {
    const float* x    = (const float*)d_in[0];
    const int*   adj  = (const int*)d_in[1];
    const float* W    = (const float*)d_in[2];
    const float* bias = (const float*)d_in[3];
    const int* nidx = adj;            // adj[0] row: node index per incidence
    const int* eidx = adj + N_INC;    // adj[1] row: edge index per incidence
    float* out = (float*)d_out;

    // ---- workspace layout (19,360,000 bytes total) ----
    char* ws = (char*)d_ws;
    float* e_feat = (float*)(ws);                     //  5,120,000
    int*   einc   = (int*)(ws + 5120000);             //  6,400,000
    int*   ninc   = (int*)(ws + 11520000);            //  6,400,000
    int*   ecnt   = (int*)(ws + 17920000);            //     80,000
    int*   ncnt   = (int*)(ws + 18000000);            //    400,000
    int*   eoff   = (int*)(ws + 18400000);            //     80,000
    int*   ecur   = (int*)(ws + 18480000);            //     80,000
    int*   noff   = (int*)(ws + 18560000);            //    400,000
    int*   ncur   = (int*)(ws + 18960000);            //    400,000

    // zero the two histograms (contiguous: ecnt then ncnt)
    hipMemsetAsync(ecnt, 0, 480000, stream);

    // degrees
    k_count<<<(N_INC + 255) / 256, 256, 0, stream>>>(nidx, eidx, ncnt, ecnt);

    // offsets + cursors
    k_scan<<<1, 1024, 0, stream>>>(ecnt, eoff, ecur, N_EDGES);
    k_scan<<<1, 1024, 0, stream>>>(ncnt, noff, ncur, N_NODES);

    // CSR incidence lists
    k_fill<<<(N_INC + 255) / 256, 256, 0, stream>>>(nidx, eidx, ecur, ncur, einc, ninc);

    // xw = x @ W  (stored in d_out; consumed before out is overwritten)
    k_gemm<<<(N_NODES + 63) / 64, 256, 0, stream>>>(x, W, out);

    // edge aggregation (pull, no atomics), fused * Binv
    k_edge_gather<<<(N_EDGES * 64) / 256, 256, 0, stream>>>(einc, eoff, ecnt, out, e_feat);

    // node aggregation (pull), fused * Dinv + bias + relu; overwrites d_out
    k_node_gather<<<(N_NODES * 64) / 256, 256, 0, stream>>>(ninc, noff, ncnt, e_feat, bias, out);
}

// Round 3
// 681.220 us; speedup vs baseline: 1.4265x; 1.4265x over previous
//
#include <hip/hip_runtime.h>

#define N_NODES 100000
#define N_EDGES 20000
#define N_INC   1600000
#define NFEAT   256
#define NCLASS  64

#define NXCD    8
#define NB8     128   // blocks per XCD-range (grid = 8*NB8)

// edge range size per XCD, node range size per XCD
#define ERANGE  (N_EDGES / NXCD)   // 2500
#define NRANGE  (N_NODES / NXCD)   // 12500

// ---------------- histogram, XCD-range partitioned ------------------------
// blocks with bid%8==r only bump counters in range r, so each counter line
// is owned by one XCD's L2. All blocks scan the full incidence list (int4).
__global__ __launch_bounds__(256) void k_count_part(const int* __restrict__ nidx,
                                                    const int* __restrict__ eidx,
                                                    int* __restrict__ ncnt,
                                                    int* __restrict__ ecnt) {
    const int r  = blockIdx.x & (NXCD - 1);
    const int b8 = blockIdx.x >> 3;
    const int elo = r * ERANGE, ehi = elo + ERANGE;
    const int nlo = r * NRANGE, nhi = nlo + NRANGE;
    const int stride = NB8 * 256 * 4;
    for (int i = (b8 * 256 + threadIdx.x) * 4; i < N_INC; i += stride) {
        const int4 e = *(const int4*)&eidx[i];
        const int4 n = *(const int4*)&nidx[i];
        if (e.x >= elo && e.x < ehi) atomicAdd(&ecnt[e.x], 1);
        if (e.y >= elo && e.y < ehi) atomicAdd(&ecnt[e.y], 1);
        if (e.z >= elo && e.z < ehi) atomicAdd(&ecnt[e.z], 1);
        if (e.w >= elo && e.w < ehi) atomicAdd(&ecnt[e.w], 1);
        if (n.x >= nlo && n.x < nhi) atomicAdd(&ncnt[n.x], 1);
        if (n.y >= nlo && n.y < nhi) atomicAdd(&ncnt[n.y], 1);
        if (n.z >= nlo && n.z < nhi) atomicAdd(&ncnt[n.z], 1);
        if (n.w >= nlo && n.w < nhi) atomicAdd(&ncnt[n.w], 1);
    }
}

// ---------------- single-block exclusive scan (int4-vectorized) ----------
__global__ __launch_bounds__(1024) void k_scan(const int* __restrict__ cnt,
                                               int* __restrict__ off,
                                               int* __restrict__ cur,
                                               int n) {
    __shared__ int part[1024];
    const int t = threadIdx.x;
    const int chunk = ((n / 4 + 1023) / 1024) * 4;   // ints per thread, %4==0
    const int lo = min(t * chunk, n);
    const int hi = min(lo + chunk, n);
    int s = 0;
    for (int i = lo; i < hi; i += 4) {
        const int4 v = *(const int4*)&cnt[i];
        s += v.x + v.y + v.z + v.w;
    }
    part[t] = s;
    __syncthreads();
    for (int d = 1; d < 1024; d <<= 1) {
        int v = (t >= d) ? part[t - d] : 0;
        __syncthreads();
        part[t] += v;
        __syncthreads();
    }
    int run = (t == 0) ? 0 : part[t - 1];
    for (int i = lo; i < hi; i += 4) {
        const int4 v = *(const int4*)&cnt[i];
        int4 o;
        o.x = run; run += v.x;
        o.y = run; run += v.y;
        o.z = run; run += v.z;
        o.w = run; run += v.w;
        *(int4*)&off[i] = o;
        *(int4*)&cur[i] = o;
    }
}

// ---------------- CSR fill, XCD-range partitioned -------------------------
// einc[slot] = node-id grouped by edge; ninc[slot] = edge-id grouped by node.
// Range ownership keeps every output cache line written by a single XCD.
__global__ __launch_bounds__(256) void k_fill_part(const int* __restrict__ nidx,
                                                   const int* __restrict__ eidx,
                                                   int* __restrict__ ecur,
                                                   int* __restrict__ ncur,
                                                   int* __restrict__ einc,
                                                   int* __restrict__ ninc) {
    const int r  = blockIdx.x & (NXCD - 1);
    const int b8 = blockIdx.x >> 3;
    const int elo = r * ERANGE, ehi = elo + ERANGE;
    const int nlo = r * NRANGE, nhi = nlo + NRANGE;
    const int stride = NB8 * 256 * 4;
    for (int i = (b8 * 256 + threadIdx.x) * 4; i < N_INC; i += stride) {
        const int4 e = *(const int4*)&eidx[i];
        const int4 n = *(const int4*)&nidx[i];
        if (e.x >= elo && e.x < ehi) einc[atomicAdd(&ecur[e.x], 1)] = n.x;
        if (e.y >= elo && e.y < ehi) einc[atomicAdd(&ecur[e.y], 1)] = n.y;
        if (e.z >= elo && e.z < ehi) einc[atomicAdd(&ecur[e.z], 1)] = n.z;
        if (e.w >= elo && e.w < ehi) einc[atomicAdd(&ecur[e.w], 1)] = n.w;
        if (n.x >= nlo && n.x < nhi) ninc[atomicAdd(&ncur[n.x], 1)] = e.x;
        if (n.y >= nlo && n.y < nhi) ninc[atomicAdd(&ncur[n.y], 1)] = e.y;
        if (n.z >= nlo && n.z < nhi) ninc[atomicAdd(&ncur[n.z], 1)] = e.z;
        if (n.w >= nlo && n.w < nhi) ninc[atomicAdd(&ncur[n.w], 1)] = e.w;
    }
}

// ---------------- xw = x @ W  (fp32 vector GEMM, 64x64 tile) --------------
__global__ __launch_bounds__(256) void k_gemm(const float* __restrict__ x,
                                              const float* __restrict__ W,
                                              float* __restrict__ xw) {
    __shared__ float xs[64][68];
    __shared__ float wt[64][64];
    const int t  = threadIdx.x;
    const int tr = t >> 4;
    const int tc = t & 15;
    const int block_row = blockIdx.x * 64;

    float acc[4][4] = {};

    for (int k0 = 0; k0 < NFEAT; k0 += 64) {
        {
            const int rr = t >> 2;
            const int q  = t & 3;
            const int grow = block_row + rr;
            #pragma unroll
            for (int it = 0; it < 4; ++it) {
                const int kk = q * 4 + it * 16;
                float4 v = make_float4(0.f, 0.f, 0.f, 0.f);
                if (grow < N_NODES)
                    v = *(const float4*)&x[(size_t)grow * NFEAT + k0 + kk];
                xs[kk + 0][rr] = v.x;
                xs[kk + 1][rr] = v.y;
                xs[kk + 2][rr] = v.z;
                xs[kk + 3][rr] = v.w;
            }
        }
        {
            #pragma unroll
            for (int it = 0; it < 4; ++it) {
                const int k = tr + it * 16;
                *(float4*)&wt[k][tc * 4] =
                    *(const float4*)&W[(size_t)(k0 + k) * NCLASS + tc * 4];
            }
        }
        __syncthreads();

        #pragma unroll 16
        for (int kk = 0; kk < 64; ++kk) {
            const float4 xv = *(const float4*)&xs[kk][tr * 4];
            const float4 wv = *(const float4*)&wt[kk][tc * 4];
            const float xa[4] = {xv.x, xv.y, xv.z, xv.w};
            const float wa[4] = {wv.x, wv.y, wv.z, wv.w};
            #pragma unroll
            for (int i2 = 0; i2 < 4; ++i2)
                #pragma unroll
                for (int j2 = 0; j2 < 4; ++j2)
                    acc[i2][j2] = fmaf(xa[i2], wa[j2], acc[i2][j2]);
        }
        __syncthreads();
    }

    #pragma unroll
    for (int i2 = 0; i2 < 4; ++i2) {
        const int r = block_row + tr * 4 + i2;
        if (r < N_NODES) {
            float4 v = make_float4(acc[i2][0], acc[i2][1], acc[i2][2], acc[i2][3]);
            *(float4*)&xw[(size_t)r * NCLASS + tc * 4] = v;
        }
    }
}

// ---------------- per-edge pull gather (one wave per edge, lane=channel) --
__global__ __launch_bounds__(256) void k_edge_gather(const int* __restrict__ einc,
                                                     const int* __restrict__ eoff,
                                                     const int* __restrict__ ecnt,
                                                     const float* __restrict__ xw,
                                                     float* __restrict__ e_feat) {
    const int wave = (blockIdx.x * 256 + threadIdx.x) >> 6;
    const int lane = threadIdx.x & 63;
    if (wave >= N_EDGES) return;
    const int base = eoff[wave];
    const int deg  = ecnt[wave];
    float a0 = 0.f, a1 = 0.f, a2 = 0.f, a3 = 0.f;
    int j = base;
    const int end = base + deg;
    for (; j + 4 <= end; j += 4) {
        const int n0 = einc[j], n1 = einc[j + 1], n2 = einc[j + 2], n3 = einc[j + 3];
        a0 += xw[(size_t)n0 * NCLASS + lane];
        a1 += xw[(size_t)n1 * NCLASS + lane];
        a2 += xw[(size_t)n2 * NCLASS + lane];
        a3 += xw[(size_t)n3 * NCLASS + lane];
    }
    for (; j < end; ++j) a0 += xw[(size_t)einc[j] * NCLASS + lane];
    const float s = (a0 + a1) + (a2 + a3);
    e_feat[(size_t)wave * NCLASS + lane] = (deg > 0) ? s / (float)deg : 0.f;
}

// ---------------- per-node pull gather + Dinv + bias + relu ---------------
__global__ __launch_bounds__(256) void k_node_gather(const int* __restrict__ ninc,
                                                     const int* __restrict__ noff,
                                                     const int* __restrict__ ncnt,
                                                     const float* __restrict__ e_feat,
                                                     const float* __restrict__ b,
                                                     float* __restrict__ out) {
    const int wave = (blockIdx.x * 256 + threadIdx.x) >> 6;
    const int lane = threadIdx.x & 63;
    if (wave >= N_NODES) return;
    const int base = noff[wave];
    const int deg  = ncnt[wave];
    float a0 = 0.f, a1 = 0.f, a2 = 0.f, a3 = 0.f;
    int j = base;
    const int end = base + deg;
    for (; j + 4 <= end; j += 4) {
        const int e0 = ninc[j], e1 = ninc[j + 1], e2 = ninc[j + 2], e3 = ninc[j + 3];
        a0 += e_feat[(size_t)e0 * NCLASS + lane];
        a1 += e_feat[(size_t)e1 * NCLASS + lane];
        a2 += e_feat[(size_t)e2 * NCLASS + lane];
        a3 += e_feat[(size_t)e3 * NCLASS + lane];
    }
    for (; j < end; ++j) a0 += e_feat[(size_t)ninc[j] * NCLASS + lane];
    const float s = (a0 + a1) + (a2 + a3);
    const float r = (deg > 0) ? s / (float)deg : 0.f;
    out[(size_t)wave * NCLASS + lane] = fmaxf(r + b[lane], 0.f);
}

extern "C" void kernel_launch(void* const* d_in, const int* in_sizes, int n_in,
                              void* d_out, int out_size, void* d_ws, size_t ws_size,
                              hipStream_t stream) {
    const float* x    = (const float*)d_in[0];
    const int*   adj  = (const int*)d_in[1];
    const float* W    = (const float*)d_in[2];
    const float* bias = (const float*)d_in[3];
    const int* nidx = adj;            // adj[0]: node index per incidence
    const int* eidx = adj + N_INC;    // adj[1]: edge index per incidence
    float* out = (float*)d_out;

    // ---- workspace layout (19,360,000 bytes) ----
    char* ws = (char*)d_ws;
    float* e_feat = (float*)(ws);                     //  5,120,000
    int*   einc   = (int*)(ws + 5120000);             //  6,400,000
    int*   ninc   = (int*)(ws + 11520000);            //  6,400,000
    int*   ecnt   = (int*)(ws + 17920000);            //     80,000
    int*   ncnt   = (int*)(ws + 18000000);            //    400,000
    int*   eoff   = (int*)(ws + 18400000);            //     80,000
    int*   ecur   = (int*)(ws + 18480000);            //     80,000
    int*   noff   = (int*)(ws + 18560000);            //    400,000
    int*   ncur   = (int*)(ws + 18960000);            //    400,000

    // zero histograms (ecnt + ncnt contiguous)
    hipMemsetAsync(ecnt, 0, 480000, stream);

    // degrees (XCD-range partitioned)
    k_count_part<<<NXCD * NB8, 256, 0, stream>>>(nidx, eidx, ncnt, ecnt);

    // offsets + fill cursors
    k_scan<<<1, 1024, 0, stream>>>(ecnt, eoff, ecur, N_EDGES);
    k_scan<<<1, 1024, 0, stream>>>(ncnt, noff, ncur, N_NODES);

    // CSR incidence lists (XCD-range partitioned)
    k_fill_part<<<NXCD * NB8, 256, 0, stream>>>(nidx, eidx, ecur, ncur, einc, ninc);

    // xw = x @ W  (stored in d_out; consumed before out is overwritten)
    k_gemm<<<(N_NODES + 63) / 64, 256, 0, stream>>>(x, W, out);

    // edge aggregation (pull), fused * Binv
    k_edge_gather<<<(N_EDGES * 64) / 256, 256, 0, stream>>>(einc, eoff, ecnt, out, e_feat);

    // node aggregation (pull), fused * Dinv + bias + relu
    k_node_gather<<<(N_NODES * 64) / 256, 256, 0, stream>>>(ninc, noff, ncnt, e_feat, bias, out);
}